// Round 10
// baseline (62.012 us; speedup 1.0000x reference)
//
#include <hip/hip_runtime.h>
#include <hip/hip_bf16.h>

// Sizes (fixed by the reference)
#define BATCH 2
#define SEQ   4096
#define DIM   256
#define HEADS 8
#define HDIM  32
#define M_ROWS (BATCH * SEQ)   // 8192
#define FPSCALE 4294967296.0   // 2^32 fixed-point scale
#define ATTNROWS 4
#define ATTNBLKS (M_ROWS / ATTNROWS)  // 2048
#define LNBLKS (M_ROWS / 2)           // 4096

typedef short bf16x8 __attribute__((ext_vector_type(8)));
typedef unsigned short u16x8 __attribute__((ext_vector_type(8)));
typedef float f32x4 __attribute__((ext_vector_type(4)));

static __device__ inline unsigned short f2bf(float x) {
  union { float f; unsigned u; } v; v.f = x;
  unsigned r = v.u + 0x7FFF + ((v.u >> 16) & 1);   // round-nearest-even
  return (unsigned short)(r >> 16);
}

// ---------------------------------------------------------------------------
// K0: prep — Wt[n][k] = bf16(Wcat[k][n]); y==0 blocks zero yctx/wacc/ctr
// (re-zeroed every launch -> graph-replay safe, stream-ordered).
// ---------------------------------------------------------------------------
__global__ __launch_bounds__(256) void k_prep(const float* __restrict__ Wl,
                                              const float* __restrict__ Wr,
                                              unsigned short* __restrict__ Wt,
                                              unsigned long long* __restrict__ yctx,
                                              unsigned long long* __restrict__ wacc,
                                              unsigned* __restrict__ ctr) {
  if (blockIdx.y == 0) {
    const int idx = blockIdx.x * 256 + threadIdx.x;   // [0, 2048)
    if (idx < BATCH * DIM) yctx[idx] = 0ull;
    if (idx < BATCH * HEADS) wacc[idx] = 0ull;
    if (idx == 0) *ctr = 0u;
  }
  __shared__ float tile[32][33];
  const int k0 = blockIdx.x * 32;
  const int n0 = blockIdx.y * 32;
  const int t = threadIdx.x;
  const float* W = (n0 < 256) ? Wl : Wr;
  const int nb = n0 & 255;
  {
    const int r = t >> 3;            // k-local
    const int c = (t & 7) * 4;       // n-local
    const float4 v = *(const float4*)(&W[(size_t)(k0 + r) * DIM + nb + c]);
    tile[r][c + 0] = v.x; tile[r][c + 1] = v.y;
    tile[r][c + 2] = v.z; tile[r][c + 3] = v.w;
  }
  __syncthreads();
  {
    const int nl = t >> 3;           // n-local
    const int kl = (t & 7) * 4;      // k-local
    ushort4 o;
    o.x = f2bf(tile[kl + 0][nl]); o.y = f2bf(tile[kl + 1][nl]);
    o.z = f2bf(tile[kl + 2][nl]); o.w = f2bf(tile[kl + 3][nl]);
    *(ushort4*)(&Wt[(size_t)(n0 + nl) * DIM + k0 + kl]) = o;
  }
}

// ---------------------------------------------------------------------------
// K1: fused MFMA GEMM + score/context epilogue + LAST-BLOCK fh2.
// Block (bm, isR): 64 rows x 256 cols of (isR ? fr : fl); wave = head.
// msl/msr written; isR blocks accumulate unnormalized context + wsum via
// exact i64 fixed-point atomics (fr never hits global).
// Last-block-done (NO __threadfence — R5 lesson): __syncthreads() drains
// vmcnt (compiler emits full s_waitcnt before s_barrier), so this block's
// atomics are performed at L2 before its counter bump; 256th bump => all
// adds done. Last block atomic-reads accumulators, normalizes, matvec Wf.
// Deterministic: final i64 values unique, fixed matvec order.
// ---------------------------------------------------------------------------
__global__ __launch_bounds__(512) void k_gemm_fused(
    const float* __restrict__ A, const unsigned short* __restrict__ Wt,
    const float* __restrict__ a_l, const float* __restrict__ a_r,
    const float* __restrict__ Wf,
    float* __restrict__ msl, float* __restrict__ msr,
    unsigned long long* __restrict__ yctx,
    unsigned long long* __restrict__ wacc,
    unsigned* __restrict__ ctr,
    float* __restrict__ fh2) {
  __shared__ unsigned short As[64 * 32];    // 4 KB
  __shared__ unsigned short Bs[256 * 32];   // 16 KB
  __shared__ float red[64][8];              // per-row per-head scores
  __shared__ float c_sh[BATCH * DIM];       // last-block context
  __shared__ unsigned done_s;

  const int bid = blockIdx.x;
  const int isR = bid & 1;
  const int bm  = bid >> 1;       // 128 row tiles of 64
  const int m0 = bm * 64;
  const int n0 = isR * 256;       // Wt row offset (0: W_l, 256: W_r)

  const int t = threadIdx.x;
  const int lane = t & 63;
  const int wid = t >> 6;         // wave = head 0..7 (cols wid*32..+32)

  f32x4 acc[4][2];
  #pragma unroll
  for (int i = 0; i < 4; ++i)
    #pragma unroll
    for (int j = 0; j < 2; ++j) acc[i][j] = (f32x4){0.f, 0.f, 0.f, 0.f};

  for (int k0 = 0; k0 < DIM; k0 += 32) {
    if (t < 256) {
      const int row = t >> 2;
      const int kc = t & 3;
      const int slot = kc ^ ((row >> 1) & 3);
      const float4 a0 = *(const float4*)(&A[(size_t)(m0 + row) * DIM + k0 + kc * 8]);
      const float4 a1 = *(const float4*)(&A[(size_t)(m0 + row) * DIM + k0 + kc * 8 + 4]);
      u16x8 pa;
      pa[0] = f2bf(a0.x); pa[1] = f2bf(a0.y); pa[2] = f2bf(a0.z); pa[3] = f2bf(a0.w);
      pa[4] = f2bf(a1.x); pa[5] = f2bf(a1.y); pa[6] = f2bf(a1.z); pa[7] = f2bf(a1.w);
      *(u16x8*)((char*)As + row * 64 + slot * 16) = pa;
    }
    #pragma unroll
    for (int p = 0; p < 2; ++p) {
      const int task = t + p * 512;
      const int row = task >> 2;      // 0..255
      const int kc = task & 3;
      const int slot = kc ^ ((row >> 1) & 3);
      const u16x8 pb = *(const u16x8*)(&Wt[(size_t)(n0 + row) * DIM + k0 + kc * 8]);
      *(u16x8*)((char*)Bs + row * 64 + slot * 16) = pb;
    }
    __syncthreads();

    bf16x8 af[4], bfr[2];
    #pragma unroll
    for (int mr = 0; mr < 4; ++mr) {
      const int ra = mr * 16 + (lane & 15);
      const int sl = (lane >> 4) ^ ((ra >> 1) & 3);
      af[mr] = *(const bf16x8*)((const char*)As + ra * 64 + sl * 16);
    }
    #pragma unroll
    for (int nr = 0; nr < 2; ++nr) {
      const int cb = wid * 32 + nr * 16 + (lane & 15);
      const int sl = (lane >> 4) ^ ((cb >> 1) & 3);
      bfr[nr] = *(const bf16x8*)((const char*)Bs + cb * 64 + sl * 16);
    }
    #pragma unroll
    for (int mr = 0; mr < 4; ++mr)
      #pragma unroll
      for (int nr = 0; nr < 2; ++nr)
        acc[mr][nr] = __builtin_amdgcn_mfma_f32_16x16x32_bf16(af[mr], bfr[nr], acc[mr][nr], 0, 0, 0);
    __syncthreads();
  }

  // ---- epilogue. C/D layout: row = mr*16 + (lane>>4)*4 + r, col = lane&15.
  const float* av = isR ? a_r : a_l;
  const int b = m0 >> 12;

  float e[4][4];      // exp(score) per owned row (isR only use)
  #pragma unroll
  for (int mr = 0; mr < 4; ++mr) {
    #pragma unroll
    for (int r = 0; r < 4; ++r) {
      float p = 0.f;
      #pragma unroll
      for (int nr = 0; nr < 2; ++nr) {
        float x = acc[mr][nr][r];
        x = x >= 0.f ? x : 0.01f * x;
        p = fmaf(x, av[nr * 16 + (lane & 15)], p);
      }
      #pragma unroll
      for (int o = 1; o < 16; o <<= 1) p += __shfl_xor(p, o, 16);
      if ((lane & 15) == 0) {
        const int rl = mr * 16 + (lane >> 4) * 4 + r;
        red[rl][wid] = p;
      }
      e[mr][r] = __expf(p);
    }
  }

  if (isR) {
    float se = 0.f;
    #pragma unroll
    for (int mr = 0; mr < 4; ++mr)
      #pragma unroll
      for (int r = 0; r < 4; ++r) se += e[mr][r];
    se += __shfl_xor(se, 16, 64);
    se += __shfl_xor(se, 32, 64);
    if (lane == 0)
      atomicAdd(&wacc[b * HEADS + wid],
                (unsigned long long)__double2ll_rn((double)se * FPSCALE));
    #pragma unroll
    for (int nr = 0; nr < 2; ++nr) {
      float y = 0.f;
      #pragma unroll
      for (int mr = 0; mr < 4; ++mr)
        #pragma unroll
        for (int r = 0; r < 4; ++r)
          y = fmaf(e[mr][r], acc[mr][nr][r], y);
      y += __shfl_xor(y, 16, 64);
      y += __shfl_xor(y, 32, 64);
      if (lane < 16)
        atomicAdd(&yctx[(size_t)b * DIM + wid * 32 + nr * 16 + lane],
                  (unsigned long long)__double2ll_rn((double)y * FPSCALE));
    }
  }
  __syncthreads();   // drains vmcnt: this block's atomics performed at L2
  if (t < 64) {
    float s = 0.f;
    #pragma unroll
    for (int h2 = 0; h2 < 8; ++h2) s += red[t][h2];
    (isR ? msr : msl)[m0 + t] = s * 0.125f;
  }

  // ---- last-block-done fh2 (runs once, after all 256 blocks' atomics)
  if (t == 0) done_s = atomicAdd(ctr, 1u);
  __syncthreads();
  if (done_s == 255u) {
    {
      const int b2 = t >> 8, d = t & 255;
      const unsigned long long yv = atomicAdd(&yctx[t], 0ull);           // L2 read
      const unsigned long long wv = atomicAdd(&wacc[b2 * HEADS + (d >> 5)], 0ull);
      c_sh[t] = (float)((double)(long long)yv / (double)(long long)wv);
    }
    __syncthreads();
    const int b2 = t >> 8, n = t & 255;
    float a2 = 0.f;
    #pragma unroll 8
    for (int k = 0; k < DIM; ++k)
      a2 = fmaf(c_sh[b2 * DIM + k], Wf[(size_t)k * DIM + n], a2);
    fh2[b2 * DIM + n] = a2;
  }
}

// ---------------------------------------------------------------------------
// K2: final output dispatch — attn streaming write + LayerNorm, merged.
// Blocks [0, ATTNBLKS): attn, 4 rows each, msr staged in 16 regs.
// Blocks [ATTNBLKS, ATTNBLKS+LNBLKS): LN, 2 rows each (R8's proven shape).
// Both depend only on the gemm dispatch; both are pure streaming.
// ---------------------------------------------------------------------------
__global__ __launch_bounds__(256) void k_out(const float* __restrict__ h,
                                             const float* __restrict__ fh2,
                                             const float* __restrict__ g,
                                             const float* __restrict__ bb,
                                             const float* __restrict__ msl,
                                             const float* __restrict__ msr,
                                             float* __restrict__ out,
                                             float* __restrict__ attn) {
  const int blk = blockIdx.x;
  const int t = threadIdx.x;

  if (blk < ATTNBLKS) {
    const int row0 = blk * ATTNROWS;
    const int b = row0 >> 12;
    f32x4 m[4];
    const f32x4* mr4 = (const f32x4*)(msr + ((size_t)b << 12));
    #pragma unroll
    for (int q = 0; q < 4; ++q) m[q] = mr4[q * 256 + t];
    #pragma unroll
    for (int rr = 0; rr < ATTNROWS; ++rr) {
      const float v = msl[row0 + rr];
      f32x4* dst = (f32x4*)(attn + ((size_t)(row0 + rr) << 12));
      #pragma unroll
      for (int q = 0; q < 4; ++q)
        __builtin_nontemporal_store(m[q] + v, &dst[q * 256 + t]);
    }
    return;
  }

  const int row0 = (blk - ATTNBLKS) * 2;
  const int b = row0 >> 12;
  const float fh = fh2[b * DIM + t];
  const float x0 = h[(size_t)row0 * DIM + t] + fh;
  const float x1 = h[(size_t)(row0 + 1) * DIM + t] + fh;
  float s10 = x0, s20 = x0 * x0, s11 = x1, s21 = x1 * x1;
  #pragma unroll
  for (int o = 32; o > 0; o >>= 1) {
    s10 += __shfl_xor(s10, o, 64);
    s20 += __shfl_xor(s20, o, 64);
    s11 += __shfl_xor(s11, o, 64);
    s21 += __shfl_xor(s21, o, 64);
  }
  __shared__ float r1[2][4], r2[2][4];
  if ((t & 63) == 0) {
    r1[0][t >> 6] = s10; r2[0][t >> 6] = s20;
    r1[1][t >> 6] = s11; r2[1][t >> 6] = s21;
  }
  __syncthreads();
  const float gs = g[t], bs = bb[t];
  {
    const float s1 = r1[0][0] + r1[0][1] + r1[0][2] + r1[0][3];
    const float s2 = r2[0][0] + r2[0][1] + r2[0][2] + r2[0][3];
    const float mu = s1 * (1.f / 256.f);
    const float var = s2 * (1.f / 256.f) - mu * mu;
    const float rs = rsqrtf(var + 1e-5f);
    out[(size_t)row0 * DIM + t] = (x0 - mu) * rs * gs + bs;
  }
  {
    const float s1 = r1[1][0] + r1[1][1] + r1[1][2] + r1[1][3];
    const float s2 = r2[1][0] + r2[1][1] + r2[1][2] + r2[1][3];
    const float mu = s1 * (1.f / 256.f);
    const float var = s2 * (1.f / 256.f) - mu * mu;
    const float rs = rsqrtf(var + 1e-5f);
    out[(size_t)(row0 + 1) * DIM + t] = (x1 - mu) * rs * gs + bs;
  }
}

// ---------------------------------------------------------------------------
extern "C" void kernel_launch(void* const* d_in, const int* in_sizes, int n_in,
                              void* d_out, int out_size, void* d_ws, size_t ws_size,
                              hipStream_t stream) {
  const float* h  = (const float*)d_in[0];
  const float* Wl = (const float*)d_in[1];
  const float* Wr = (const float*)d_in[2];
  const float* al = (const float*)d_in[3];
  const float* ar = (const float*)d_in[4];
  const float* Wf = (const float*)d_in[5];
  const float* g  = (const float*)d_in[6];
  const float* bb = (const float*)d_in[7];
  float* out = (float*)d_out;

  unsigned long long* yctx = (unsigned long long*)d_ws;         // 512 i64
  unsigned long long* wacc = yctx + BATCH * DIM;                // 16 i64
  unsigned long long* ctrq = wacc + BATCH * HEADS;              // 1 i64 slot
  unsigned* ctr = (unsigned*)ctrq;
  float* msl = (float*)(ctrq + 1);                              // 8,192 f32
  float* msr = msl + M_ROWS;                                    // 8,192
  float* fh2 = msr + M_ROWS;                                    // 512
  unsigned short* Wt = (unsigned short*)(fh2 + BATCH * DIM);    // 512*256 u16

  k_prep<<<dim3(8, 16), 256, 0, stream>>>(Wl, Wr, Wt, yctx, wacc, ctr);
  k_gemm_fused<<<256, 512, 0, stream>>>(h, Wt, al, ar, Wf, msl, msr,
                                        yctx, wacc, ctr, fh2);
  k_out<<<ATTNBLKS + LNBLKS, 256, 0, stream>>>(h, fh2, g, bb, msl, msr,
                                               out, out + (size_t)M_ROWS * DIM);
}

// Round 11
// 59.402 us; speedup vs baseline: 1.0439x; 1.0439x over previous
//
#include <hip/hip_runtime.h>
#include <hip/hip_bf16.h>

// Sizes (fixed by the reference)
#define BATCH 2
#define SEQ   4096
#define DIM   256
#define HEADS 8
#define HDIM  32
#define M_ROWS (BATCH * SEQ)   // 8192
#define FPSCALE 4294967296.0   // 2^32 fixed-point scale
#define ATTN_V4 ((size_t)BATCH * SEQ * SEQ / 4)   // 8,388,608 f32x4
#define ATTN_BLKS 2048

typedef short bf16x8 __attribute__((ext_vector_type(8)));
typedef unsigned short u16x8 __attribute__((ext_vector_type(8)));
typedef float f32x4 __attribute__((ext_vector_type(4)));

static __device__ inline unsigned short f2bf(float x) {
  union { float f; unsigned u; } v; v.f = x;
  unsigned r = v.u + 0x7FFF + ((v.u >> 16) & 1);   // round-nearest-even
  return (unsigned short)(r >> 16);
}

// ---------------------------------------------------------------------------
// K0: prep — Wt[n][k] = bf16(Wcat[k][n]); y==0 blocks zero yctx/wacc
// (re-zeroed every launch -> graph-replay safe, stream-ordered).
// ---------------------------------------------------------------------------
__global__ __launch_bounds__(256) void k_prep(const float* __restrict__ Wl,
                                              const float* __restrict__ Wr,
                                              unsigned short* __restrict__ Wt,
                                              unsigned long long* __restrict__ yctx,
                                              unsigned long long* __restrict__ wacc) {
  if (blockIdx.y == 0) {
    const int idx = blockIdx.x * 256 + threadIdx.x;   // [0, 2048)
    if (idx < BATCH * DIM) yctx[idx] = 0ull;
    if (idx < BATCH * HEADS) wacc[idx] = 0ull;
  }
  __shared__ float tile[32][33];
  const int k0 = blockIdx.x * 32;
  const int n0 = blockIdx.y * 32;
  const int t = threadIdx.x;
  const float* W = (n0 < 256) ? Wl : Wr;
  const int nb = n0 & 255;
  {
    const int r = t >> 3;            // k-local
    const int c = (t & 7) * 4;       // n-local
    const float4 v = *(const float4*)(&W[(size_t)(k0 + r) * DIM + nb + c]);
    tile[r][c + 0] = v.x; tile[r][c + 1] = v.y;
    tile[r][c + 2] = v.z; tile[r][c + 3] = v.w;
  }
  __syncthreads();
  {
    const int nl = t >> 3;           // n-local
    const int kl = (t & 7) * 4;      // k-local
    ushort4 o;
    o.x = f2bf(tile[kl + 0][nl]); o.y = f2bf(tile[kl + 1][nl]);
    o.z = f2bf(tile[kl + 2][nl]); o.w = f2bf(tile[kl + 3][nl]);
    *(ushort4*)(&Wt[(size_t)(n0 + nl) * DIM + k0 + kl]) = o;
  }
}

// ---------------------------------------------------------------------------
// K1: fused MFMA GEMM + score/context epilogue (byte-identical to R8).
// Block (bm, isR): 64 rows x 256 cols of (isR ? fr : fl); wave = head.
// msl/msr written; isR blocks accumulate unnormalized context + wsum via
// exact i64 fixed-point atomics. fr never hits global.
// ---------------------------------------------------------------------------
__global__ __launch_bounds__(512) void k_gemm_fused(
    const float* __restrict__ A, const unsigned short* __restrict__ Wt,
    const float* __restrict__ a_l, const float* __restrict__ a_r,
    float* __restrict__ msl, float* __restrict__ msr,
    unsigned long long* __restrict__ yctx,
    unsigned long long* __restrict__ wacc) {
  __shared__ unsigned short As[64 * 32];    // 4 KB
  __shared__ unsigned short Bs[256 * 32];   // 16 KB
  __shared__ float red[64][8];              // per-row per-head scores

  const int bid = blockIdx.x;
  const int isR = bid & 1;
  const int bm  = bid >> 1;       // 128 row tiles of 64
  const int m0 = bm * 64;
  const int n0 = isR * 256;       // Wt row offset (0: W_l, 256: W_r)

  const int t = threadIdx.x;
  const int lane = t & 63;
  const int wid = t >> 6;         // wave = head 0..7 (cols wid*32..+32)

  f32x4 acc[4][2];
  #pragma unroll
  for (int i = 0; i < 4; ++i)
    #pragma unroll
    for (int j = 0; j < 2; ++j) acc[i][j] = (f32x4){0.f, 0.f, 0.f, 0.f};

  for (int k0 = 0; k0 < DIM; k0 += 32) {
    if (t < 256) {
      const int row = t >> 2;
      const int kc = t & 3;
      const int slot = kc ^ ((row >> 1) & 3);
      const float4 a0 = *(const float4*)(&A[(size_t)(m0 + row) * DIM + k0 + kc * 8]);
      const float4 a1 = *(const float4*)(&A[(size_t)(m0 + row) * DIM + k0 + kc * 8 + 4]);
      u16x8 pa;
      pa[0] = f2bf(a0.x); pa[1] = f2bf(a0.y); pa[2] = f2bf(a0.z); pa[3] = f2bf(a0.w);
      pa[4] = f2bf(a1.x); pa[5] = f2bf(a1.y); pa[6] = f2bf(a1.z); pa[7] = f2bf(a1.w);
      *(u16x8*)((char*)As + row * 64 + slot * 16) = pa;
    }
    #pragma unroll
    for (int p = 0; p < 2; ++p) {
      const int task = t + p * 512;
      const int row = task >> 2;      // 0..255
      const int kc = task & 3;
      const int slot = kc ^ ((row >> 1) & 3);
      const u16x8 pb = *(const u16x8*)(&Wt[(size_t)(n0 + row) * DIM + k0 + kc * 8]);
      *(u16x8*)((char*)Bs + row * 64 + slot * 16) = pb;
    }
    __syncthreads();

    bf16x8 af[4], bfr[2];
    #pragma unroll
    for (int mr = 0; mr < 4; ++mr) {
      const int ra = mr * 16 + (lane & 15);
      const int sl = (lane >> 4) ^ ((ra >> 1) & 3);
      af[mr] = *(const bf16x8*)((const char*)As + ra * 64 + sl * 16);
    }
    #pragma unroll
    for (int nr = 0; nr < 2; ++nr) {
      const int cb = wid * 32 + nr * 16 + (lane & 15);
      const int sl = (lane >> 4) ^ ((cb >> 1) & 3);
      bfr[nr] = *(const bf16x8*)((const char*)Bs + cb * 64 + sl * 16);
    }
    #pragma unroll
    for (int mr = 0; mr < 4; ++mr)
      #pragma unroll
      for (int nr = 0; nr < 2; ++nr)
        acc[mr][nr] = __builtin_amdgcn_mfma_f32_16x16x32_bf16(af[mr], bfr[nr], acc[mr][nr], 0, 0, 0);
    __syncthreads();
  }

  // ---- epilogue. C/D layout: row = mr*16 + (lane>>4)*4 + r, col = lane&15.
  const float* av = isR ? a_r : a_l;
  const int b = m0 >> 12;

  float e[4][4];      // exp(score) per owned row (isR only use)
  #pragma unroll
  for (int mr = 0; mr < 4; ++mr) {
    #pragma unroll
    for (int r = 0; r < 4; ++r) {
      float p = 0.f;
      #pragma unroll
      for (int nr = 0; nr < 2; ++nr) {
        float x = acc[mr][nr][r];
        x = x >= 0.f ? x : 0.01f * x;
        p = fmaf(x, av[nr * 16 + (lane & 15)], p);
      }
      #pragma unroll
      for (int o = 1; o < 16; o <<= 1) p += __shfl_xor(p, o, 16);
      if ((lane & 15) == 0) {
        const int rl = mr * 16 + (lane >> 4) * 4 + r;
        red[rl][wid] = p;
      }
      e[mr][r] = __expf(p);
    }
  }

  if (isR) {
    float se = 0.f;
    #pragma unroll
    for (int mr = 0; mr < 4; ++mr)
      #pragma unroll
      for (int r = 0; r < 4; ++r) se += e[mr][r];
    se += __shfl_xor(se, 16, 64);
    se += __shfl_xor(se, 32, 64);
    if (lane == 0)
      atomicAdd(&wacc[b * HEADS + wid],
                (unsigned long long)__double2ll_rn((double)se * FPSCALE));
    #pragma unroll
    for (int nr = 0; nr < 2; ++nr) {
      float y = 0.f;
      #pragma unroll
      for (int mr = 0; mr < 4; ++mr)
        #pragma unroll
        for (int r = 0; r < 4; ++r)
          y = fmaf(e[mr][r], acc[mr][nr][r], y);
      y += __shfl_xor(y, 16, 64);
      y += __shfl_xor(y, 32, 64);
      if (lane < 16)
        atomicAdd(&yctx[(size_t)b * DIM + wid * 32 + nr * 16 + lane],
                  (unsigned long long)__double2ll_rn((double)y * FPSCALE));
    }
  }
  __syncthreads();
  if (t < 64) {
    float s = 0.f;
    #pragma unroll
    for (int h2 = 0; h2 < 8; ++h2) s += red[t][h2];
    (isR ? msr : msl)[m0 + t] = s * 0.125f;
  }
}

// ---------------------------------------------------------------------------
// K2: fh (blocks 0,1) + FILL-STYLE grid-stride attn writer (blocks 2..2049).
// attn flat v4 index: row = idx>>10, col = idx&1023; per iter one msl scalar
// (L1), one msr v4 (L2-resident 32KB), one nt store — mimics the 6.7+ TB/s
// fill kernel's access pattern (grid-stride, many small writes in flight).
// ---------------------------------------------------------------------------
__global__ __launch_bounds__(256) void k_attn_fh(
    const float* __restrict__ msl, const float* __restrict__ msr,
    const unsigned long long* __restrict__ yctx,
    const unsigned long long* __restrict__ wacc,
    const float* __restrict__ Wf,
    float* __restrict__ fh2, float* __restrict__ attn) {
  const int blk = blockIdx.x;
  const int t = threadIdx.x;

  if (blk < BATCH) {   // fh block: normalize ctx, matvec W_final
    const int b = blk;
    __shared__ float c_s[DIM];
    c_s[t] = (float)((double)(long long)yctx[(size_t)b * DIM + t] /
                     (double)(long long)wacc[b * HEADS + (t >> 5)]);
    __syncthreads();
    float a2 = 0.f;
    #pragma unroll 8
    for (int k = 0; k < DIM; ++k)
      a2 = fmaf(c_s[k], Wf[(size_t)k * DIM + t], a2);
    fh2[b * DIM + t] = a2;
    return;
  }

  const size_t nth = (size_t)ATTN_BLKS * 256;
  size_t idx = (size_t)(blk - BATCH) * 256 + t;
  const f32x4* mr4 = (const f32x4*)msr;     // [2][1024] f32x4
  f32x4* dst = (f32x4*)attn;
  #pragma unroll 4
  for (; idx < ATTN_V4; idx += nth) {
    const size_t row = idx >> 10;           // 0..8191
    const int col = (int)(idx & 1023);
    const int bq = (int)(row >> 12) << 10;
    const float v = msl[row];
    const f32x4 m = mr4[bq + col];
    __builtin_nontemporal_store(m + v, &dst[idx]);
  }
}

// ---------------------------------------------------------------------------
// K3: LayerNorm(h + fh2[b]) -> out, 2 rows per block (R8's proven shape).
// ---------------------------------------------------------------------------
__global__ __launch_bounds__(256) void k_ln(const float* __restrict__ h,
                                            const float* __restrict__ fh2,
                                            const float* __restrict__ g,
                                            const float* __restrict__ bb,
                                            float* __restrict__ out) {
  const int row0 = blockIdx.x * 2;
  const int b = row0 >> 12;
  const int t = threadIdx.x;

  const float fh = fh2[b * DIM + t];
  const float x0 = h[(size_t)row0 * DIM + t] + fh;
  const float x1 = h[(size_t)(row0 + 1) * DIM + t] + fh;
  float s10 = x0, s20 = x0 * x0, s11 = x1, s21 = x1 * x1;
  #pragma unroll
  for (int o = 32; o > 0; o >>= 1) {
    s10 += __shfl_xor(s10, o, 64);
    s20 += __shfl_xor(s20, o, 64);
    s11 += __shfl_xor(s11, o, 64);
    s21 += __shfl_xor(s21, o, 64);
  }
  __shared__ float r1[2][4], r2[2][4];
  if ((t & 63) == 0) {
    r1[0][t >> 6] = s10; r2[0][t >> 6] = s20;
    r1[1][t >> 6] = s11; r2[1][t >> 6] = s21;
  }
  __syncthreads();
  const float gs = g[t], bs = bb[t];
  {
    const float s1 = r1[0][0] + r1[0][1] + r1[0][2] + r1[0][3];
    const float s2 = r2[0][0] + r2[0][1] + r2[0][2] + r2[0][3];
    const float mu = s1 * (1.f / 256.f);
    const float var = s2 * (1.f / 256.f) - mu * mu;
    const float rs = rsqrtf(var + 1e-5f);
    out[(size_t)row0 * DIM + t] = (x0 - mu) * rs * gs + bs;
  }
  {
    const float s1 = r1[1][0] + r1[1][1] + r1[1][2] + r1[1][3];
    const float s2 = r2[1][0] + r2[1][1] + r2[1][2] + r2[1][3];
    const float mu = s1 * (1.f / 256.f);
    const float var = s2 * (1.f / 256.f) - mu * mu;
    const float rs = rsqrtf(var + 1e-5f);
    out[(size_t)(row0 + 1) * DIM + t] = (x1 - mu) * rs * gs + bs;
  }
}

// ---------------------------------------------------------------------------
extern "C" void kernel_launch(void* const* d_in, const int* in_sizes, int n_in,
                              void* d_out, int out_size, void* d_ws, size_t ws_size,
                              hipStream_t stream) {
  const float* h  = (const float*)d_in[0];
  const float* Wl = (const float*)d_in[1];
  const float* Wr = (const float*)d_in[2];
  const float* al = (const float*)d_in[3];
  const float* ar = (const float*)d_in[4];
  const float* Wf = (const float*)d_in[5];
  const float* g  = (const float*)d_in[6];
  const float* bb = (const float*)d_in[7];
  float* out = (float*)d_out;

  unsigned long long* yctx = (unsigned long long*)d_ws;         // 512 i64
  unsigned long long* wacc = yctx + BATCH * DIM;                // 16 i64
  float* msl = (float*)(wacc + BATCH * HEADS);                  // 8,192 f32
  float* msr = msl + M_ROWS;                                    // 8,192
  float* fh2 = msr + M_ROWS;                                    // 512
  unsigned short* Wt = (unsigned short*)(fh2 + BATCH * DIM);    // 512*256 u16

  k_prep<<<dim3(8, 16), 256, 0, stream>>>(Wl, Wr, Wt, yctx, wacc);
  k_gemm_fused<<<256, 512, 0, stream>>>(h, Wt, al, ar, msl, msr, yctx, wacc);
  k_attn_fh<<<BATCH + ATTN_BLKS, 256, 0, stream>>>(msl, msr, yctx, wacc, Wf,
                                                   fh2, out + (size_t)M_ROWS * DIM);
  k_ln<<<M_ROWS / 2, 256, 0, stream>>>(h, fh2, g, bb, out);
}